// Round 3
// baseline (583.553 us; speedup 1.0000x reference)
//
#include <hip/hip_runtime.h>
#include <stdint.h>

#define NB   2
#define NN   6
#define NIMG 12
#define CIN  512
#define CMID 512
#define DD   112
#define COUT 80
#define FHh  16
#define FWw  44
#define NPIX 704
#define NPOS 8448
#define KK   4608       // 512*9, k = r*512 + ic
#define NXg  128
#define NYg  128
#define YX   16384
#define MAT_STRIDE 56
#define PADPIX 828      // 18*46 padded image
#define PROW 46

typedef short short8 __attribute__((ext_vector_type(8)));
typedef float f32x4  __attribute__((ext_vector_type(4)));

#define GLD16(g, l) __builtin_amdgcn_global_load_lds((const __attribute__((address_space(1))) void*)(g), (__attribute__((address_space(3))) void*)(l), 16, 0, 0)

__device__ __forceinline__ unsigned short f2bf(float f){
  unsigned u = __float_as_uint(f);
  u += 0x7fffu + ((u >> 16) & 1u);    // RNE
  return (unsigned short)(u >> 16);
}

__device__ __forceinline__ f32x4 mfma16(short8 a, short8 b, f32x4 c){
  return __builtin_amdgcn_mfma_f32_16x16x32_bf16(a, b, c, 0, 0, 0);
}

// ---------------- prep kernels ----------------
__global__ void k_f32_to_bf16(const float* __restrict__ src, unsigned short* __restrict__ dst, int n){
  for (int i = blockIdx.x*blockDim.x + threadIdx.x; i < n; i += gridDim.x*blockDim.x)
    dst[i] = f2bf(src[i]);
}

// w [oc][ic][3][3] -> [oc][r*512+ic] bf16
__global__ void k_wreorder(const float* __restrict__ src, unsigned short* __restrict__ dst){
  int i = blockIdx.x*blockDim.x + threadIdx.x;   // 512*4608 exactly
  int oc = i / KK; int j = i - oc*KK;
  int r = j >> 9; int ic = j & 511;
  dst[i] = f2bf(src[(size_t)(oc*512 + ic)*9 + r]);
}

__global__ void k_bn_prep(const float* __restrict__ g, const float* __restrict__ b,
                          const float* __restrict__ m, const float* __restrict__ v,
                          float* __restrict__ scale, float* __restrict__ bias){
  int t = blockIdx.x*blockDim.x + threadIdx.x;
  if (t < CMID){
    float s = g[t] / sqrtf(v[t] + 1e-5f);
    scale[t] = s;
    bias[t]  = b[t] - m[t]*s;
  }
}

// feat fp32 NCHW -> padded channels-last bf16 [img][PADPIX][512]
__global__ void k_featpad(const float* __restrict__ feat, unsigned short* __restrict__ dst){
  int blk = blockIdx.x;                 // img*16 + y, 192 blocks
  int img = blk >> 4, y = blk & 15;
  const float* s = feat + (size_t)img*CIN*NPIX + y*FWw;
  unsigned short* d = dst + (size_t)img*PADPIX*512 + ((y+1)*PROW + 1)*512;
  for (int j = threadIdx.x; j < FWw*512; j += 256){
    int x = j >> 9, ic = j & 511;
    d[x*512 + ic] = f2bf(s[(size_t)ic*NPIX + x]);
  }
}

__device__ void inv4(const double* A, double* out){
  double M[4][8];
  for (int i=0;i<4;i++){ for(int j=0;j<4;j++){ M[i][j]=A[i*4+j]; M[i][4+j]=(i==j)?1.0:0.0; } }
  for (int c=0;c<4;c++){
    int piv=c; double best=fabs(M[c][c]);
    for (int r=c+1;r<4;r++){ double a=fabs(M[r][c]); if(a>best){best=a;piv=r;} }
    if (piv!=c){ for(int j=0;j<8;j++){ double tt=M[c][j]; M[c][j]=M[piv][j]; M[piv][j]=tt; } }
    double inv = 1.0 / M[c][c];
    for (int j=0;j<8;j++) M[c][j]*=inv;
    for (int r=0;r<4;r++){ if(r==c) continue; double f=M[r][c];
      for (int j=0;j<8;j++) M[r][j]-=f*M[c][j]; }
  }
  for (int i=0;i<4;i++) for(int j=0;j<4;j++) out[i*4+j]=M[i][4+j];
}
__device__ void mm4(const double* A, const double* Bm, double* C){
  for (int i=0;i<4;i++) for(int j=0;j<4;j++){
    double s=0.0; for(int k=0;k<4;k++) s+=A[i*4+k]*Bm[k*4+j]; C[i*4+j]=s; }
}

__global__ void k_prep_mats(const float* __restrict__ s2e, const float* __restrict__ s2v,
                            const float* __restrict__ intr, const float* __restrict__ ida,
                            const float* __restrict__ refh, const float* __restrict__ bda,
                            double* __restrict__ mats){
  int t = threadIdx.x;
  if (t >= NIMG) return;
  int b = t / NN;
  double Mida[16], Ms2v[16], Mintr[16], Ms2e[16], Mbda[16];
  for (int i=0;i<16;i++){
    Mida[i] =(double)ida [t*16+i];
    Ms2v[i] =(double)s2v [t*16+i];
    Mintr[i]=(double)intr[t*16+i];
    Ms2e[i] =(double)s2e [t*16+i];
    Mbda[i] =(double)bda [b*16+i];
  }
  double* o = mats + (size_t)t*MAT_STRIDE;
  double tmp[16], tmp2[16];
  inv4(Mida, o);
  inv4(Mintr, tmp);  mm4(Ms2v, tmp, o+16);
  inv4(Ms2v, tmp);   mm4(Ms2e, tmp, tmp2);
  mm4(Mbda, tmp2, o+32);
  o[48] = (double)refh[t];
}

// ---------------- geometry ----------------
__global__ void k_geom(const double* __restrict__ mats, int* __restrict__ sid){
  int g = blockIdx.x*blockDim.x + threadIdx.x;       // 946176 exactly
  int img = g / (DD*NPIX); int rem = g - img*(DD*NPIX);
  int d = rem / NPIX; int p = rem - d*NPIX;
  int h = p / FWw; int w = p - h*FWw;
  const double* M = mats + (size_t)img*MAT_STRIDE;
  float xf = (float)w * (703.0f/43.0f);
  float yf = (float)h * 17.0f;
  float df = 2.0f + (float)d * (56.0f/111.0f);
  double x = (double)xf, y = (double)yf, dep = (double)df;
  double p0 = M[0]*x + M[1]*y + M[2]*dep + M[3];
  double p1 = M[4]*x + M[5]*y + M[6]*dep + M[7];
  double p2 = M[8]*x + M[9]*y + M[10]*dep + M[11];
  double p3 = M[12]*x + M[13]*y + M[14]*dep + M[15];
  double height = M[48] - p2;
  double c0 = p0*10.0, c1 = p1*10.0, c2 = 10.0, c3 = p3;
  const double* C = M + 16;
  double q0 = C[0]*c0 + C[1]*c1 + C[2]*c2 + C[3]*c3;
  double q1 = C[4]*c0 + C[5]*c1 + C[6]*c2 + C[7]*c3;
  double q2 = C[8]*c0 + C[9]*c1 + C[10]*c2 + C[11]*c3;
  double ratio = height / q1;
  double r0 = q0*ratio, r1 = q1*ratio, r2 = q2*ratio, r3 = 1.0;
  const double* F = M + 32;
  double gx = F[0]*r0 + F[1]*r1 + F[2]*r2 + F[3]*r3;
  double gy = F[4]*r0 + F[5]*r1 + F[6]*r2 + F[7]*r3;
  double gz = F[8]*r0 + F[9]*r1 + F[10]*r2 + F[11]*r3;
  float gxf = (float)gx, gyf = (float)gy, gzf = (float)gz;
  const float vcx = (float)(-51.2 + 0.4);
  const float ox = vcx - 0.4f;
  const float oy = ox;
  const float oz = -1.0f - 4.0f;
  float tx = (gxf - ox) / 0.8f;
  float ty = (gyf - oy) / 0.8f;
  float tz = (gzf - oz) / 8.0f;
  int ix = (int)tx, iy = (int)ty, iz = (int)tz;
  bool valid = (tx==tx) && (ty==ty) && (tz==tz) &&
               (ix >= 0) && (ix < NXg) && (iy >= 0) && (iy < NYg) && (iz == 0);
  int b = img / NN;
  sid[g] = valid ? (b*YX + iy*NXg + ix) : -1;
}

// ---------------- conv GEMM: single-wave blocks, vmcnt-pipelined, no barriers ----------------
// Each block = 1 wave computing 64(oc) x 64(pos). DEPTH=4 LDS buffers, prefetch dist 3.
// W [512][4608] bf16 (k=r*512+ic), src padded NHWC bf16 [12][828][512].
template<int OUT_PADDED>
__global__ __launch_bounds__(64) void k_conv_p(const unsigned short* __restrict__ W,
    const unsigned short* __restrict__ src,
    const float* __restrict__ scale, const float* __restrict__ bias,
    unsigned short* __restrict__ out){
  __shared__ __align__(16) short As[4*64*32];   // 16 KB
  __shared__ __align__(16) short Bs[4*64*32];   // 16 KB
  int lane = threadIdx.x;
  int q = lane >> 4, ml = lane & 15;
  int m0 = blockIdx.x * 64;
  int n0 = blockIdx.y * 64;

  int lrow = lane >> 2;          // 0..15
  int lch  = (lane & 3) * 8;     // shorts within 32-short k slice
  const unsigned short* aptr = W + (size_t)(m0 + lrow)*KK + lch;
  const unsigned short* bptr[4];
  #pragma unroll
  for (int i=0;i<4;i++){
    int pos = n0 + i*16 + lrow;
    int img = pos / NPIX; int p = pos - img*NPIX;
    int y = p / FWw; int x = p - y*FWw;
    bptr[i] = src + (size_t)img*PADPIX*512 + ((y+1)*PROW + (x+1))*512 + lch;
  }

  f32x4 acc[4][4];
  #pragma unroll
  for (int i=0;i<4;i++)
    #pragma unroll
    for (int j=0;j<4;j++) acc[i][j] = (f32x4)0.0f;

  auto stage = [&](int s, int d){
    int kb = s*32;
    int r = kb >> 9, ic0 = kb & 511;
    int r3 = r/3;
    int koff = (r3*PROW + (r - r3*3))*512 + ic0 - (PROW+1)*512;
    #pragma unroll
    for (int i=0;i<4;i++){
      GLD16(aptr + (size_t)i*16*KK + kb, (char*)As + d*4096 + i*1024);
      GLD16(bptr[i] + koff,              (char*)Bs + d*4096 + i*1024);
    }
  };

  const int NSTEP = KK/32;   // 144
  stage(0,0); stage(1,1); stage(2,2); stage(3,3);

  for (int k = 0; k < NSTEP; ++k){
    int d = k & 3;
    // step k's 8 loads are the oldest; allow the 24 newer (steps k+1..k+3) to stay in flight
    asm volatile("s_waitcnt vmcnt(24)" ::: "memory");
    const short* Ab = As + d*2048;
    const short* Bb = Bs + d*2048;
    short8 fa[4], fb[4];
    #pragma unroll
    for (int mi=0;mi<4;mi++) fa[mi] = *(const short8*)(Ab + (mi*16 + ml)*32 + q*8);
    #pragma unroll
    for (int ni=0;ni<4;ni++) fb[ni] = *(const short8*)(Bb + (ni*16 + ml)*32 + q*8);
    #pragma unroll
    for (int mi=0;mi<4;mi++)
      #pragma unroll
      for (int ni=0;ni<4;ni++)
        acc[mi][ni] = mfma16(fb[ni], fa[mi], acc[mi][ni]);   // D rows=pos, cols=oc
    if (k + 4 < NSTEP) stage(k + 4, d);
  }

  #pragma unroll
  for (int mi=0;mi<4;mi++){
    int oc = m0 + mi*16 + ml;
    float s = scale[oc], bb = bias[oc];
    #pragma unroll
    for (int ni=0;ni<4;ni++){
      f32x4 v = acc[mi][ni];
      #pragma unroll
      for (int rr=0;rr<4;rr++){
        int pos = n0 + ni*16 + q*4 + rr;
        float val = fmaxf(v[rr]*s + bb, 0.0f);
        if (OUT_PADDED){
          int img = pos / NPIX; int p = pos - img*NPIX;
          int y = p / FWw; int x = p - y*FWw;
          out[(size_t)img*PADPIX*512 + ((y+1)*PROW + (x+1))*512 + oc] = f2bf(val);
        } else {
          out[(size_t)pos*CMID + oc] = f2bf(val);
        }
      }
    }
  }
}

// ---------------- 1x1 conv-out GEMM: M=192(BM=64), N=8448, K=512 ----------------
__global__ __launch_bounds__(256) void k_gemm64(const unsigned short* __restrict__ A,
    const unsigned short* __restrict__ Bt, const float* __restrict__ bout,
    float* __restrict__ hf){
  const int K = 512;
  __shared__ __align__(16) short As[64][32];
  __shared__ __align__(16) short Bs[128][32];
  int t = threadIdx.x;
  int m0 = blockIdx.x*64; int n0 = blockIdx.y*128;
  int lane = t & 63; int wv = t >> 6; int q = lane >> 4, ml = lane & 15;
  f32x4 acc[8];
  #pragma unroll
  for (int i=0;i<8;i++) acc[i] = (f32x4)0.0f;
  int ar = t >> 2, ac = (t & 3) * 8;
  int br = t >> 1, bc = (t & 1) * 16;
  const unsigned short* pa = A  + (size_t)(m0 + ar)*K + ac;
  const unsigned short* pb = Bt + (size_t)(n0 + br)*K + bc;
  for (int kb = 0; kb < K; kb += 32){
    uint4 av = *(const uint4*)(pa + kb);
    uint4 b0 = *(const uint4*)(pb + kb);
    uint4 b1 = *(const uint4*)(pb + kb + 8);
    __syncthreads();
    *(uint4*)&As[ar][ac] = av;
    *(uint4*)&Bs[br][bc] = b0; *(uint4*)&Bs[br][bc+8] = b1;
    __syncthreads();
    short8 fa = *(const short8*)&As[wv*16 + ml][q*8];
    #pragma unroll
    for (int ni=0;ni<8;ni++){
      short8 fb = *(const short8*)&Bs[ni*16 + ml][q*8];
      acc[ni] = mfma16(fb, fa, acc[ni]);     // rows = pos, cols = oc
    }
  }
  int oc = m0 + wv*16 + ml;
  float bb = bout[oc];
  #pragma unroll
  for (int ni=0;ni<8;ni++)
    #pragma unroll
    for (int r=0;r<4;r++){
      int pos = n0 + ni*16 + q*4 + r;
      hf[(size_t)pos*192 + oc] = acc[ni][r] + bb;
    }
}

// ---------------- depth softmax ----------------
__global__ void k_softmax(const float* __restrict__ hf, float* __restrict__ depth){
  int pos = blockIdx.x*4 + (threadIdx.x >> 6);
  int lane = threadIdx.x & 63;
  const float* row = hf + (size_t)pos*192;
  float v0 = row[lane];
  float v1 = (lane < DD-64) ? row[64 + lane] : -1e30f;
  float mx = fmaxf(v0, v1);
  #pragma unroll
  for (int m=1; m<64; m<<=1) mx = fmaxf(mx, __shfl_xor(mx, m, 64));
  float e0 = expf(v0 - mx);
  float e1 = (lane < DD-64) ? expf(v1 - mx) : 0.0f;
  float s = e0 + e1;
  #pragma unroll
  for (int m=1; m<64; m<<=1) s += __shfl_xor(s, m, 64);
  float inv = 1.0f / s;
  depth[(size_t)pos*DD + lane] = e0 * inv;
  if (lane < DD-64) depth[(size_t)pos*DD + 64 + lane] = e1 * inv;
}

// ---------------- scatter: head-compaction then dense atomic loop ----------------
__global__ void k_scatter(const float* __restrict__ depth, const float* __restrict__ hf,
                          const int* __restrict__ sidb, float* __restrict__ bev){
  int pos = blockIdx.x;
  int img = pos / NPIX; int p = pos - img*NPIX;
  __shared__ float sdep[DD];
  __shared__ int   ssid[DD];
  __shared__ float sctx[COUT];
  __shared__ float cwt[DD];
  __shared__ int   cvox[DD];
  __shared__ int   scnt;
  int t = threadIdx.x;    // 128
  if (t == 0) scnt = 0;
  if (t < DD){
    sdep[t] = depth[(size_t)pos*DD + t];
    ssid[t] = sidb[(size_t)(img*DD + t)*NPIX + p];
  }
  if (t < COUT) sctx[t] = hf[(size_t)pos*192 + DD + t];
  __syncthreads();
  if (t < DD){
    int s = ssid[t];
    bool head = (s >= 0) && (t == 0 || ssid[t-1] != s);
    if (head){
      float w = 0.0f;
      for (int dd = t; dd < DD && ssid[dd] == s; ++dd) w += sdep[dd];
      int i = atomicAdd(&scnt, 1);
      cvox[i] = s; cwt[i] = w;
    }
  }
  __syncthreads();
  int H = scnt;
  for (int j = t; j < H*COUT; j += 128){
    int h = j / COUT, c = j - h*COUT;
    atomicAdd(&bev[(size_t)cvox[h]*COUT + c], cwt[h]*sctx[c]);
  }
}

// ---------------- final transpose ----------------
__global__ void k_transpose(const float* __restrict__ bev, float* __restrict__ out){
  int i = blockIdx.x*blockDim.x + threadIdx.x;   // 2621440 exactly
  int yx = i & (YX-1); int rest = i >> 14;
  int c = rest % COUT; int b = rest / COUT;
  out[i] = bev[((size_t)(b*YX + yx))*COUT + c];
}

// ---------------- host ----------------
extern "C" void kernel_launch(void* const* d_in, const int* in_sizes, int n_in,
                              void* d_out, int out_size, void* d_ws, size_t ws_size,
                              hipStream_t stream) {
  const float* feat = (const float*)d_in[0];
  const float* w1   = (const float*)d_in[1];
  const float* g1   = (const float*)d_in[2];
  const float* b1   = (const float*)d_in[3];
  const float* m1   = (const float*)d_in[4];
  const float* v1   = (const float*)d_in[5];
  const float* w2   = (const float*)d_in[6];
  const float* g2   = (const float*)d_in[7];
  const float* b2   = (const float*)d_in[8];
  const float* m2   = (const float*)d_in[9];
  const float* v2   = (const float*)d_in[10];
  const float* wout = (const float*)d_in[11];
  const float* bout = (const float*)d_in[12];
  const float* s2e  = (const float*)d_in[13];
  const float* s2v  = (const float*)d_in[14];
  const float* intr = (const float*)d_in[15];
  const float* ida  = (const float*)d_in[16];
  const float* refh = (const float*)d_in[17];
  const float* bda  = (const float*)d_in[18];

  uint8_t* base = (uint8_t*)d_ws;
  size_t off = 0;
  auto alloc = [&](size_t bytes)->void*{
    void* r = base + off;
    off = (off + bytes + 255) & ~(size_t)255;
    return r;
  };
  unsigned short* wb1 = (unsigned short*)alloc((size_t)CMID*KK*2);
  unsigned short* wb2 = (unsigned short*)alloc((size_t)CMID*KK*2);
  unsigned short* wb3 = (unsigned short*)alloc((size_t)192*CMID*2);
  float* scale1 = (float*)alloc(CMID*4);
  float* bias1  = (float*)alloc(CMID*4);
  float* scale2 = (float*)alloc(CMID*4);
  float* bias2  = (float*)alloc(CMID*4);
  double* mats  = (double*)alloc((size_t)NIMG*MAT_STRIDE*8);

  size_t padded_bytes = (size_t)NIMG*PADPIX*512*2;          // 10.2 MB
  uint8_t* regionE = (uint8_t*)alloc(padded_bytes);
  uint8_t* regionF = (uint8_t*)alloc(padded_bytes);
  float* depth = (float*)alloc((size_t)NPOS*DD*4);
  int*   sid   = (int*)  alloc((size_t)NIMG*DD*NPIX*4);
  float* bev   = (float*)alloc((size_t)NB*YX*COUT*4);

  unsigned short* featpad = (unsigned short*)regionE;
  unsigned short* h2      = (unsigned short*)regionE;
  unsigned short* h1pad   = (unsigned short*)regionF;
  float*          hf      = (float*)regionF;

  // prep
  k_wreorder<<<9216, 256, 0, stream>>>(w1, wb1);
  k_wreorder<<<9216, 256, 0, stream>>>(w2, wb2);
  k_f32_to_bf16<<<384, 256, 0, stream>>>(wout, wb3, 192*CMID);
  k_bn_prep<<<2, 256, 0, stream>>>(g1, b1, m1, v1, scale1, bias1);
  k_bn_prep<<<2, 256, 0, stream>>>(g2, b2, m2, v2, scale2, bias2);
  k_prep_mats<<<1, 64, 0, stream>>>(s2e, s2v, intr, ida, refh, bda, mats);
  k_geom<<<3696, 256, 0, stream>>>(mats, sid);

  hipMemsetAsync(featpad, 0, padded_bytes, stream);
  hipMemsetAsync(h1pad,   0, padded_bytes, stream);
  k_featpad<<<192, 256, 0, stream>>>(feat, featpad);

  // conv1: featpad -> h1pad (padded NHWC bf16); 1056 single-wave blocks
  k_conv_p<1><<<dim3(8, 132), 64, 0, stream>>>(wb1, featpad, scale1, bias1, h1pad);
  // conv2: h1pad -> h2 ([pos][512] bf16)
  k_conv_p<0><<<dim3(8, 132), 64, 0, stream>>>(wb2, h1pad, scale2, bias2, h2);
  // conv3 (1x1): h2 -> hf ([pos][192] fp32, +b_out)
  k_gemm64<<<dim3(3, 66), 256, 0, stream>>>(wb3, h2, bout, hf);

  k_softmax<<<2112, 256, 0, stream>>>(hf, depth);

  hipMemsetAsync(bev, 0, (size_t)NB*YX*COUT*4, stream);
  k_scatter<<<NPOS, 128, 0, stream>>>(depth, hf, sid, bev);

  k_transpose<<<10240, 256, 0, stream>>>(bev, (float*)d_out);
}

// Round 4
// 423.951 us; speedup vs baseline: 1.3765x; 1.3765x over previous
//
#include <hip/hip_runtime.h>
#include <stdint.h>

#define NB   2
#define NN   6
#define NIMG 12
#define CIN  512
#define CMID 512
#define DD   112
#define COUT 80
#define FHh  16
#define FWw  44
#define NPIX 704
#define NPOS 8448
#define KK   4608       // 512*9, k = r*512 + ic
#define NXg  128
#define NYg  128
#define YX   16384
#define MAT_STRIDE 56
#define PADPIX 828      // 18*46 padded image
#define PROW 46
#define KSPLIT 4
#define KCHUNK (KK/KSPLIT)   // 1152

typedef short short8 __attribute__((ext_vector_type(8)));
typedef float f32x4  __attribute__((ext_vector_type(4)));

#define GLD16(g, l) __builtin_amdgcn_global_load_lds((const __attribute__((address_space(1))) void*)(g), (__attribute__((address_space(3))) void*)(l), 16, 0, 0)

__device__ __forceinline__ unsigned short f2bf(float f){
  unsigned u = __float_as_uint(f);
  u += 0x7fffu + ((u >> 16) & 1u);    // RNE
  return (unsigned short)(u >> 16);
}

__device__ __forceinline__ f32x4 mfma16(short8 a, short8 b, f32x4 c){
  return __builtin_amdgcn_mfma_f32_16x16x32_bf16(a, b, c, 0, 0, 0);
}

// ---------------- prep kernels ----------------
__global__ void k_f32_to_bf16(const float* __restrict__ src, unsigned short* __restrict__ dst, int n){
  for (int i = blockIdx.x*blockDim.x + threadIdx.x; i < n; i += gridDim.x*blockDim.x)
    dst[i] = f2bf(src[i]);
}

// w [oc][ic][3][3] -> [oc][r*512+ic] bf16
__global__ void k_wreorder(const float* __restrict__ src, unsigned short* __restrict__ dst){
  int i = blockIdx.x*blockDim.x + threadIdx.x;   // 512*4608 exactly
  int oc = i / KK; int j = i - oc*KK;
  int r = j >> 9; int ic = j & 511;
  dst[i] = f2bf(src[(size_t)(oc*512 + ic)*9 + r]);
}

__global__ void k_bn_prep(const float* __restrict__ g, const float* __restrict__ b,
                          const float* __restrict__ m, const float* __restrict__ v,
                          float* __restrict__ scale, float* __restrict__ bias){
  int t = blockIdx.x*blockDim.x + threadIdx.x;
  if (t < CMID){
    float s = g[t] / sqrtf(v[t] + 1e-5f);
    scale[t] = s;
    bias[t]  = b[t] - m[t]*s;
  }
}

// feat fp32 NCHW -> padded channels-last bf16 [img][PADPIX][512]
__global__ void k_featpad(const float* __restrict__ feat, unsigned short* __restrict__ dst){
  int blk = blockIdx.x;                 // img*16 + y, 192 blocks
  int img = blk >> 4, y = blk & 15;
  const float* s = feat + (size_t)img*CIN*NPIX + y*FWw;
  unsigned short* d = dst + (size_t)img*PADPIX*512 + ((y+1)*PROW + 1)*512;
  for (int j = threadIdx.x; j < FWw*512; j += 256){
    int x = j >> 9, ic = j & 511;
    d[x*512 + ic] = f2bf(s[(size_t)ic*NPIX + x]);
  }
}

__device__ void inv4(const double* A, double* out){
  double M[4][8];
  for (int i=0;i<4;i++){ for(int j=0;j<4;j++){ M[i][j]=A[i*4+j]; M[i][4+j]=(i==j)?1.0:0.0; } }
  for (int c=0;c<4;c++){
    int piv=c; double best=fabs(M[c][c]);
    for (int r=c+1;r<4;r++){ double a=fabs(M[r][c]); if(a>best){best=a;piv=r;} }
    if (piv!=c){ for(int j=0;j<8;j++){ double tt=M[c][j]; M[c][j]=M[piv][j]; M[piv][j]=tt; } }
    double inv = 1.0 / M[c][c];
    for (int j=0;j<8;j++) M[c][j]*=inv;
    for (int r=0;r<4;r++){ if(r==c) continue; double f=M[r][c];
      for (int j=0;j<8;j++) M[r][j]-=f*M[c][j]; }
  }
  for (int i=0;i<4;i++) for(int j=0;j<4;j++) out[i*4+j]=M[i][4+j];
}
__device__ void mm4(const double* A, const double* Bm, double* C){
  for (int i=0;i<4;i++) for(int j=0;j<4;j++){
    double s=0.0; for(int k=0;k<4;k++) s+=A[i*4+k]*Bm[k*4+j]; C[i*4+j]=s; }
}

__global__ void k_prep_mats(const float* __restrict__ s2e, const float* __restrict__ s2v,
                            const float* __restrict__ intr, const float* __restrict__ ida,
                            const float* __restrict__ refh, const float* __restrict__ bda,
                            double* __restrict__ mats){
  int t = threadIdx.x;
  if (t >= NIMG) return;
  int b = t / NN;
  double Mida[16], Ms2v[16], Mintr[16], Ms2e[16], Mbda[16];
  for (int i=0;i<16;i++){
    Mida[i] =(double)ida [t*16+i];
    Ms2v[i] =(double)s2v [t*16+i];
    Mintr[i]=(double)intr[t*16+i];
    Ms2e[i] =(double)s2e [t*16+i];
    Mbda[i] =(double)bda [b*16+i];
  }
  double* o = mats + (size_t)t*MAT_STRIDE;
  double tmp[16], tmp2[16];
  inv4(Mida, o);
  inv4(Mintr, tmp);  mm4(Ms2v, tmp, o+16);
  inv4(Ms2v, tmp);   mm4(Ms2e, tmp, tmp2);
  mm4(Mbda, tmp2, o+32);
  o[48] = (double)refh[t];
}

// ---------------- geometry ----------------
__global__ void k_geom(const double* __restrict__ mats, int* __restrict__ sid){
  int g = blockIdx.x*blockDim.x + threadIdx.x;       // 946176 exactly
  int img = g / (DD*NPIX); int rem = g - img*(DD*NPIX);
  int d = rem / NPIX; int p = rem - d*NPIX;
  int h = p / FWw; int w = p - h*FWw;
  const double* M = mats + (size_t)img*MAT_STRIDE;
  float xf = (float)w * (703.0f/43.0f);
  float yf = (float)h * 17.0f;
  float df = 2.0f + (float)d * (56.0f/111.0f);
  double x = (double)xf, y = (double)yf, dep = (double)df;
  double p0 = M[0]*x + M[1]*y + M[2]*dep + M[3];
  double p1 = M[4]*x + M[5]*y + M[6]*dep + M[7];
  double p2 = M[8]*x + M[9]*y + M[10]*dep + M[11];
  double p3 = M[12]*x + M[13]*y + M[14]*dep + M[15];
  double height = M[48] - p2;
  double c0 = p0*10.0, c1 = p1*10.0, c2 = 10.0, c3 = p3;
  const double* C = M + 16;
  double q0 = C[0]*c0 + C[1]*c1 + C[2]*c2 + C[3]*c3;
  double q1 = C[4]*c0 + C[5]*c1 + C[6]*c2 + C[7]*c3;
  double q2 = C[8]*c0 + C[9]*c1 + C[10]*c2 + C[11]*c3;
  double ratio = height / q1;
  double r0 = q0*ratio, r1 = q1*ratio, r2 = q2*ratio, r3 = 1.0;
  const double* F = M + 32;
  double gx = F[0]*r0 + F[1]*r1 + F[2]*r2 + F[3]*r3;
  double gy = F[4]*r0 + F[5]*r1 + F[6]*r2 + F[7]*r3;
  double gz = F[8]*r0 + F[9]*r1 + F[10]*r2 + F[11]*r3;
  float gxf = (float)gx, gyf = (float)gy, gzf = (float)gz;
  const float vcx = (float)(-51.2 + 0.4);
  const float ox = vcx - 0.4f;
  const float oy = ox;
  const float oz = -1.0f - 4.0f;
  float tx = (gxf - ox) / 0.8f;
  float ty = (gyf - oy) / 0.8f;
  float tz = (gzf - oz) / 8.0f;
  int ix = (int)tx, iy = (int)ty, iz = (int)tz;
  bool valid = (tx==tx) && (ty==ty) && (tz==tz) &&
               (ix >= 0) && (ix < NXg) && (iy >= 0) && (iy < NYg) && (iz == 0);
  int b = img / NN;
  sid[g] = valid ? (b*YX + iy*NXg + ix) : -1;
}

// ---------------- conv GEMM: split-K, implicit im2col, global_load_lds staging ----------------
// Grid (4, 66, KSPLIT). Each block: 128(oc) x 128(pos) over K-chunk blockIdx.z.
// Writes fp32 partials part[s][pos][oc].
__global__ __launch_bounds__(256, 4) void k_conv_sk(const unsigned short* __restrict__ W,
    const unsigned short* __restrict__ src, float* __restrict__ part){
  __shared__ __align__(16) short As[128*32];
  __shared__ __align__(16) short Bs[128*32];
  int t = threadIdx.x;
  int lane = t & 63, wv = t >> 6;
  int wm = wv >> 1, wn = wv & 1;
  int q = lane >> 4, ml = lane & 15;
  int m0 = blockIdx.x * 128;
  int n0 = blockIdx.y * 128;
  int k0 = blockIdx.z * KCHUNK;

  int lrow = lane >> 2;          // 0..15
  int lcol = (lane & 3) * 8;     // shorts
  const unsigned short* agp[2];
  const unsigned short* bgp[2];
  #pragma unroll
  for (int i=0;i<2;i++){
    int seg = wv*2 + i;
    agp[i] = W + (size_t)(m0 + seg*16 + lrow)*KK + lcol;
    int pos = n0 + seg*16 + lrow;
    int img = pos / NPIX; int p = pos - img*NPIX;
    int y = p / FWw; int x = p - y*FWw;
    bgp[i] = src + (size_t)img*PADPIX*512 + ((y+1)*PROW + (x+1))*512 + lcol;
  }

  f32x4 acc[4][4];
  #pragma unroll
  for (int i=0;i<4;i++)
    #pragma unroll
    for (int j=0;j<4;j++) acc[i][j] = (f32x4)0.0f;

  for (int kb = k0; kb < k0 + KCHUNK; kb += 32){
    int r = kb >> 9;
    int ic0 = kb & 511;
    int r3 = r / 3;
    int koff = (r3*PROW + (r - r3*3))*512 + ic0 - (PROW+1)*512;  // (dy*46+dx)*512 + ic0
    #pragma unroll
    for (int i=0;i<2;i++){
      int seg = wv*2 + i;
      GLD16(agp[i] + kb,   (char*)As + seg*1024);
      GLD16(bgp[i] + koff, (char*)Bs + seg*1024);
    }
    __syncthreads();
    short8 fa[4], fb[4];
    #pragma unroll
    for (int mi=0;mi<4;mi++) fa[mi] = *(const short8*)(As + (wm*64 + mi*16 + ml)*32 + q*8);
    #pragma unroll
    for (int ni=0;ni<4;ni++) fb[ni] = *(const short8*)(Bs + (wn*64 + ni*16 + ml)*32 + q*8);
    #pragma unroll
    for (int mi=0;mi<4;mi++)
      #pragma unroll
      for (int ni=0;ni<4;ni++)
        acc[mi][ni] = mfma16(fb[ni], fa[mi], acc[mi][ni]);   // rows=pos, cols=oc
    __syncthreads();
  }

  float* op = part + (size_t)blockIdx.z*NPOS*CMID;
  #pragma unroll
  for (int mi=0;mi<4;mi++){
    int oc = m0 + wm*64 + mi*16 + ml;
    #pragma unroll
    for (int ni=0;ni<4;ni++){
      f32x4 v = acc[mi][ni];
      #pragma unroll
      for (int rr=0;rr<4;rr++){
        int pos = n0 + wn*64 + ni*16 + q*4 + rr;
        op[(size_t)pos*CMID + oc] = v[rr];
      }
    }
  }
}

// ---------------- split-K reduce + BN + ReLU + bf16 ----------------
// OUT_PADDED=1: write padded NHWC (for conv2 input); else [pos][512].
template<int OUT_PADDED>
__global__ void k_reduce(const float* __restrict__ part,
                         const float* __restrict__ scale, const float* __restrict__ bias,
                         unsigned short* __restrict__ out){
  int i = blockIdx.x*blockDim.x + threadIdx.x;   // NPOS*CMID exactly
  int pos = i >> 9, oc = i & 511;
  const size_t S = (size_t)NPOS*CMID;
  float sum = part[i] + part[i + S] + part[i + 2*S] + part[i + 3*S];
  float val = fmaxf(sum*scale[oc] + bias[oc], 0.0f);
  unsigned short bv = f2bf(val);
  if (OUT_PADDED){
    int img = pos / NPIX; int p = pos - img*NPIX;
    int y = p / FWw; int x = p - y*FWw;
    out[(size_t)img*PADPIX*512 + ((y+1)*PROW + (x+1))*512 + oc] = bv;
  } else {
    out[i] = bv;
  }
}

// ---------------- 1x1 conv-out GEMM: M=192(BM=64), N=8448, K=512 ----------------
__global__ __launch_bounds__(256) void k_gemm64(const unsigned short* __restrict__ A,
    const unsigned short* __restrict__ Bt, const float* __restrict__ bout,
    float* __restrict__ hf){
  const int K = 512;
  __shared__ __align__(16) short As[64][32];
  __shared__ __align__(16) short Bs[128][32];
  int t = threadIdx.x;
  int m0 = blockIdx.x*64; int n0 = blockIdx.y*128;
  int lane = t & 63; int wv = t >> 6; int q = lane >> 4, ml = lane & 15;
  f32x4 acc[8];
  #pragma unroll
  for (int i=0;i<8;i++) acc[i] = (f32x4)0.0f;
  int ar = t >> 2, ac = (t & 3) * 8;
  int br = t >> 1, bc = (t & 1) * 16;
  const unsigned short* pa = A  + (size_t)(m0 + ar)*K + ac;
  const unsigned short* pb = Bt + (size_t)(n0 + br)*K + bc;
  for (int kb = 0; kb < K; kb += 32){
    uint4 av = *(const uint4*)(pa + kb);
    uint4 b0 = *(const uint4*)(pb + kb);
    uint4 b1 = *(const uint4*)(pb + kb + 8);
    __syncthreads();
    *(uint4*)&As[ar][ac] = av;
    *(uint4*)&Bs[br][bc] = b0; *(uint4*)&Bs[br][bc+8] = b1;
    __syncthreads();
    short8 fa = *(const short8*)&As[wv*16 + ml][q*8];
    #pragma unroll
    for (int ni=0;ni<8;ni++){
      short8 fb = *(const short8*)&Bs[ni*16 + ml][q*8];
      acc[ni] = mfma16(fb, fa, acc[ni]);     // rows = pos, cols = oc
    }
  }
  int oc = m0 + wv*16 + ml;
  float bb = bout[oc];
  #pragma unroll
  for (int ni=0;ni<8;ni++)
    #pragma unroll
    for (int r=0;r<4;r++){
      int pos = n0 + ni*16 + q*4 + r;
      hf[(size_t)pos*192 + oc] = acc[ni][r] + bb;
    }
}

// ---------------- depth softmax ----------------
__global__ void k_softmax(const float* __restrict__ hf, float* __restrict__ depth){
  int pos = blockIdx.x*4 + (threadIdx.x >> 6);
  int lane = threadIdx.x & 63;
  const float* row = hf + (size_t)pos*192;
  float v0 = row[lane];
  float v1 = (lane < DD-64) ? row[64 + lane] : -1e30f;
  float mx = fmaxf(v0, v1);
  #pragma unroll
  for (int m=1; m<64; m<<=1) mx = fmaxf(mx, __shfl_xor(mx, m, 64));
  float e0 = expf(v0 - mx);
  float e1 = (lane < DD-64) ? expf(v1 - mx) : 0.0f;
  float s = e0 + e1;
  #pragma unroll
  for (int m=1; m<64; m<<=1) s += __shfl_xor(s, m, 64);
  float inv = 1.0f / s;
  depth[(size_t)pos*DD + lane] = e0 * inv;
  if (lane < DD-64) depth[(size_t)pos*DD + 64 + lane] = e1 * inv;
}

// ---------------- scatter: head-compaction then dense atomic loop ----------------
__global__ void k_scatter(const float* __restrict__ depth, const float* __restrict__ hf,
                          const int* __restrict__ sidb, float* __restrict__ bev){
  int pos = blockIdx.x;
  int img = pos / NPIX; int p = pos - img*NPIX;
  __shared__ float sdep[DD];
  __shared__ int   ssid[DD];
  __shared__ float sctx[COUT];
  __shared__ float cwt[DD];
  __shared__ int   cvox[DD];
  __shared__ int   scnt;
  int t = threadIdx.x;    // 128
  if (t == 0) scnt = 0;
  if (t < DD){
    sdep[t] = depth[(size_t)pos*DD + t];
    ssid[t] = sidb[(size_t)(img*DD + t)*NPIX + p];
  }
  if (t < COUT) sctx[t] = hf[(size_t)pos*192 + DD + t];
  __syncthreads();
  if (t < DD){
    int s = ssid[t];
    bool head = (s >= 0) && (t == 0 || ssid[t-1] != s);
    if (head){
      float w = 0.0f;
      for (int dd = t; dd < DD && ssid[dd] == s; ++dd) w += sdep[dd];
      int i = atomicAdd(&scnt, 1);
      cvox[i] = s; cwt[i] = w;
    }
  }
  __syncthreads();
  int H = scnt;
  for (int j = t; j < H*COUT; j += 128){
    int h = j / COUT, c = j - h*COUT;
    atomicAdd(&bev[(size_t)cvox[h]*COUT + c], cwt[h]*sctx[c]);
  }
}

// ---------------- final transpose ----------------
__global__ void k_transpose(const float* __restrict__ bev, float* __restrict__ out){
  int i = blockIdx.x*blockDim.x + threadIdx.x;   // 2621440 exactly
  int yx = i & (YX-1); int rest = i >> 14;
  int c = rest % COUT; int b = rest / COUT;
  out[i] = bev[((size_t)(b*YX + yx))*COUT + c];
}

// ---------------- host ----------------
extern "C" void kernel_launch(void* const* d_in, const int* in_sizes, int n_in,
                              void* d_out, int out_size, void* d_ws, size_t ws_size,
                              hipStream_t stream) {
  const float* feat = (const float*)d_in[0];
  const float* w1   = (const float*)d_in[1];
  const float* g1   = (const float*)d_in[2];
  const float* b1   = (const float*)d_in[3];
  const float* m1   = (const float*)d_in[4];
  const float* v1   = (const float*)d_in[5];
  const float* w2   = (const float*)d_in[6];
  const float* g2   = (const float*)d_in[7];
  const float* b2   = (const float*)d_in[8];
  const float* m2   = (const float*)d_in[9];
  const float* v2   = (const float*)d_in[10];
  const float* wout = (const float*)d_in[11];
  const float* bout = (const float*)d_in[12];
  const float* s2e  = (const float*)d_in[13];
  const float* s2v  = (const float*)d_in[14];
  const float* intr = (const float*)d_in[15];
  const float* ida  = (const float*)d_in[16];
  const float* refh = (const float*)d_in[17];
  const float* bda  = (const float*)d_in[18];

  uint8_t* base = (uint8_t*)d_ws;
  size_t off = 0;
  auto alloc = [&](size_t bytes)->void*{
    void* r = base + off;
    off = (off + bytes + 255) & ~(size_t)255;
    return r;
  };
  unsigned short* wb1 = (unsigned short*)alloc((size_t)CMID*KK*2);
  unsigned short* wb2 = (unsigned short*)alloc((size_t)CMID*KK*2);
  unsigned short* wb3 = (unsigned short*)alloc((size_t)192*CMID*2);
  float* scale1 = (float*)alloc(CMID*4);
  float* bias1  = (float*)alloc(CMID*4);
  float* scale2 = (float*)alloc(CMID*4);
  float* bias2  = (float*)alloc(CMID*4);
  double* mats  = (double*)alloc((size_t)NIMG*MAT_STRIDE*8);

  size_t padded_bytes = (size_t)NIMG*PADPIX*512*2;          // 10.2 MB
  uint8_t* regionE = (uint8_t*)alloc(padded_bytes);
  uint8_t* regionF = (uint8_t*)alloc(padded_bytes);
  float* depth = (float*)alloc((size_t)NPOS*DD*4);
  int*   sid   = (int*)  alloc((size_t)NIMG*DD*NPIX*4);
  float* bev   = (float*)alloc((size_t)NB*YX*COUT*4);
  float* part  = (float*)alloc((size_t)KSPLIT*NPOS*CMID*4); // 69.2 MB

  unsigned short* featpad = (unsigned short*)regionE;
  unsigned short* h2      = (unsigned short*)regionE;
  unsigned short* h1pad   = (unsigned short*)regionF;
  float*          hf      = (float*)regionF;

  // prep
  k_wreorder<<<9216, 256, 0, stream>>>(w1, wb1);
  k_wreorder<<<9216, 256, 0, stream>>>(w2, wb2);
  k_f32_to_bf16<<<384, 256, 0, stream>>>(wout, wb3, 192*CMID);
  k_bn_prep<<<2, 256, 0, stream>>>(g1, b1, m1, v1, scale1, bias1);
  k_bn_prep<<<2, 256, 0, stream>>>(g2, b2, m2, v2, scale2, bias2);
  k_prep_mats<<<1, 64, 0, stream>>>(s2e, s2v, intr, ida, refh, bda, mats);
  k_geom<<<3696, 256, 0, stream>>>(mats, sid);

  hipMemsetAsync(featpad, 0, padded_bytes, stream);
  hipMemsetAsync(h1pad,   0, padded_bytes, stream);
  k_featpad<<<192, 256, 0, stream>>>(feat, featpad);

  // conv1: featpad -> partials -> h1pad (padded NHWC bf16)
  k_conv_sk<<<dim3(4, 66, KSPLIT), 256, 0, stream>>>(wb1, featpad, part);
  k_reduce<1><<<16896, 256, 0, stream>>>(part, scale1, bias1, h1pad);
  // conv2: h1pad -> partials -> h2 ([pos][512] bf16)
  k_conv_sk<<<dim3(4, 66, KSPLIT), 256, 0, stream>>>(wb2, h1pad, part);
  k_reduce<0><<<16896, 256, 0, stream>>>(part, scale2, bias2, h2);
  // conv3 (1x1): h2 -> hf ([pos][192] fp32, +b_out)
  k_gemm64<<<dim3(3, 66), 256, 0, stream>>>(wb3, h2, bout, hf);

  k_softmax<<<2112, 256, 0, stream>>>(hf, depth);

  hipMemsetAsync(bev, 0, (size_t)NB*YX*COUT*4, stream);
  k_scatter<<<NPOS, 128, 0, stream>>>(depth, hf, sid, bev);

  k_transpose<<<10240, 256, 0, stream>>>(bev, (float*)d_out);
}

// Round 5
// 394.765 us; speedup vs baseline: 1.4782x; 1.0739x over previous
//
#include <hip/hip_runtime.h>
#include <stdint.h>

#define NB   2
#define NN   6
#define NIMG 12
#define CIN  512
#define CMID 512
#define DD   112
#define COUT 80
#define FHh  16
#define FWw  44
#define NPIX 704
#define NPOS 8448
#define KK   4608       // 512*9, k = r*512 + ic
#define NXg  128
#define NYg  128
#define YX   16384
#define MAT_STRIDE 56
#define PADPIX 828      // 18*46 padded image
#define PROW 46
#define KSPLIT 4
#define KCHUNK (KK/KSPLIT)   // 1152

typedef short short8 __attribute__((ext_vector_type(8)));
typedef float f32x4  __attribute__((ext_vector_type(4)));

#define GLD16(g, l) __builtin_amdgcn_global_load_lds((const __attribute__((address_space(1))) void*)(g), (__attribute__((address_space(3))) void*)(l), 16, 0, 0)

__device__ __forceinline__ unsigned short f2bf(float f){
  unsigned u = __float_as_uint(f);
  u += 0x7fffu + ((u >> 16) & 1u);    // RNE
  return (unsigned short)(u >> 16);
}
__device__ __forceinline__ float bf2f(unsigned short u){
  return __uint_as_float(((unsigned)u) << 16);
}

__device__ __forceinline__ f32x4 mfma16(short8 a, short8 b, f32x4 c){
  return __builtin_amdgcn_mfma_f32_16x16x32_bf16(a, b, c, 0, 0, 0);
}

// ---------------- fused prep: wb1, wb2, wb3, BN scale/bias ----------------
#define N1 (CMID*KK)   // 2359296
__global__ void k_prep_misc(const float* __restrict__ w1, const float* __restrict__ w2,
                            const float* __restrict__ wout,
                            const float* __restrict__ g1, const float* __restrict__ b1,
                            const float* __restrict__ m1, const float* __restrict__ v1,
                            const float* __restrict__ g2, const float* __restrict__ b2,
                            const float* __restrict__ m2, const float* __restrict__ v2,
                            unsigned short* __restrict__ wb1, unsigned short* __restrict__ wb2,
                            unsigned short* __restrict__ wb3,
                            float* __restrict__ scale1, float* __restrict__ bias1,
                            float* __restrict__ scale2, float* __restrict__ bias2){
  int i = blockIdx.x*blockDim.x + threadIdx.x;
  if (i < 2*N1){
    const float* w = (i < N1) ? w1 : w2;
    unsigned short* wb = (i < N1) ? wb1 : wb2;
    int j = (i < N1) ? i : i - N1;
    int oc = j / KK; int jj = j - oc*KK;
    int r = jj >> 9; int ic = jj & 511;
    wb[j] = f2bf(w[(size_t)(oc*512 + ic)*9 + r]);
  } else if (i < 2*N1 + 192*CMID){
    int j = i - 2*N1;
    wb3[j] = f2bf(wout[j]);
  } else if (i < 2*N1 + 192*CMID + 512){
    int t = i - (2*N1 + 192*CMID);
    float s = g1[t] / sqrtf(v1[t] + 1e-5f);
    scale1[t] = s; bias1[t] = b1[t] - m1[t]*s;
  } else if (i < 2*N1 + 192*CMID + 1024){
    int t = i - (2*N1 + 192*CMID + 512);
    float s = g2[t] / sqrtf(v2[t] + 1e-5f);
    scale2[t] = s; bias2[t] = b2[t] - m2[t]*s;
  }
}

// ---------------- border-zero for both padded buffers ----------------
__global__ void k_zeropad(unsigned short* __restrict__ a, unsigned short* __restrict__ b){
  int i = blockIdx.x*blockDim.x + threadIdx.x;   // 12*65536 exactly
  int img = i >> 16; int j = i & 65535;
  int seg = j >> 9, ch = j & 511;
  int pp;
  if (seg < 46)       pp = seg;                       // row y=0
  else if (seg < 92)  pp = 17*PROW + (seg - 46);      // row y=17
  else { int s2 = seg - 92; int y = s2 >> 1; pp = y*PROW + ((s2 & 1) ? 45 : 0); }
  size_t off = (size_t)img*PADPIX*512 + (size_t)pp*512 + ch;
  a[off] = 0; b[off] = 0;
}

// feat fp32 NCHW -> padded channels-last bf16 [img][PADPIX][512]
__global__ void k_featpad(const float* __restrict__ feat, unsigned short* __restrict__ dst){
  int blk = blockIdx.x;                 // img*16 + y, 192 blocks
  int img = blk >> 4, y = blk & 15;
  const float* s = feat + (size_t)img*CIN*NPIX + y*FWw;
  unsigned short* d = dst + (size_t)img*PADPIX*512 + ((y+1)*PROW + 1)*512;
  for (int j = threadIdx.x; j < FWw*512; j += 256){
    int x = j >> 9, ic = j & 511;
    d[x*512 + ic] = f2bf(s[(size_t)ic*NPIX + x]);
  }
}

__device__ void inv4(const double* A, double* out){
  double M[4][8];
  for (int i=0;i<4;i++){ for(int j=0;j<4;j++){ M[i][j]=A[i*4+j]; M[i][4+j]=(i==j)?1.0:0.0; } }
  for (int c=0;c<4;c++){
    int piv=c; double best=fabs(M[c][c]);
    for (int r=c+1;r<4;r++){ double a=fabs(M[r][c]); if(a>best){best=a;piv=r;} }
    if (piv!=c){ for(int j=0;j<8;j++){ double tt=M[c][j]; M[c][j]=M[piv][j]; M[piv][j]=tt; } }
    double inv = 1.0 / M[c][c];
    for (int j=0;j<8;j++) M[c][j]*=inv;
    for (int r=0;r<4;r++){ if(r==c) continue; double f=M[r][c];
      for (int j=0;j<8;j++) M[r][j]-=f*M[c][j]; }
  }
  for (int i=0;i<4;i++) for(int j=0;j<4;j++) out[i*4+j]=M[i][4+j];
}
__device__ void mm4(const double* A, const double* Bm, double* C){
  for (int i=0;i<4;i++) for(int j=0;j<4;j++){
    double s=0.0; for(int k=0;k<4;k++) s+=A[i*4+k]*Bm[k*4+j]; C[i*4+j]=s; }
}

__global__ void k_prep_mats(const float* __restrict__ s2e, const float* __restrict__ s2v,
                            const float* __restrict__ intr, const float* __restrict__ ida,
                            const float* __restrict__ refh, const float* __restrict__ bda,
                            double* __restrict__ mats){
  int t = threadIdx.x;
  if (t >= NIMG) return;
  int b = t / NN;
  double Mida[16], Ms2v[16], Mintr[16], Ms2e[16], Mbda[16];
  for (int i=0;i<16;i++){
    Mida[i] =(double)ida [t*16+i];
    Ms2v[i] =(double)s2v [t*16+i];
    Mintr[i]=(double)intr[t*16+i];
    Ms2e[i] =(double)s2e [t*16+i];
    Mbda[i] =(double)bda [b*16+i];
  }
  double* o = mats + (size_t)t*MAT_STRIDE;
  double tmp[16], tmp2[16];
  inv4(Mida, o);
  inv4(Mintr, tmp);  mm4(Ms2v, tmp, o+16);
  inv4(Ms2v, tmp);   mm4(Ms2e, tmp, tmp2);
  mm4(Mbda, tmp2, o+32);
  o[48] = (double)refh[t];
}

// ---------------- geometry ----------------
__global__ void k_geom(const double* __restrict__ mats, int* __restrict__ sid){
  int g = blockIdx.x*blockDim.x + threadIdx.x;       // 946176 exactly
  int img = g / (DD*NPIX); int rem = g - img*(DD*NPIX);
  int d = rem / NPIX; int p = rem - d*NPIX;
  int h = p / FWw; int w = p - h*FWw;
  const double* M = mats + (size_t)img*MAT_STRIDE;
  float xf = (float)w * (703.0f/43.0f);
  float yf = (float)h * 17.0f;
  float df = 2.0f + (float)d * (56.0f/111.0f);
  double x = (double)xf, y = (double)yf, dep = (double)df;
  double p0 = M[0]*x + M[1]*y + M[2]*dep + M[3];
  double p1 = M[4]*x + M[5]*y + M[6]*dep + M[7];
  double p2 = M[8]*x + M[9]*y + M[10]*dep + M[11];
  double p3 = M[12]*x + M[13]*y + M[14]*dep + M[15];
  double height = M[48] - p2;
  double c0 = p0*10.0, c1 = p1*10.0, c2 = 10.0, c3 = p3;
  const double* C = M + 16;
  double q0 = C[0]*c0 + C[1]*c1 + C[2]*c2 + C[3]*c3;
  double q1 = C[4]*c0 + C[5]*c1 + C[6]*c2 + C[7]*c3;
  double q2 = C[8]*c0 + C[9]*c1 + C[10]*c2 + C[11]*c3;
  double ratio = height / q1;
  double r0 = q0*ratio, r1 = q1*ratio, r2 = q2*ratio, r3 = 1.0;
  const double* F = M + 32;
  double gx = F[0]*r0 + F[1]*r1 + F[2]*r2 + F[3]*r3;
  double gy = F[4]*r0 + F[5]*r1 + F[6]*r2 + F[7]*r3;
  double gz = F[8]*r0 + F[9]*r1 + F[10]*r2 + F[11]*r3;
  float gxf = (float)gx, gyf = (float)gy, gzf = (float)gz;
  const float vcx = (float)(-51.2 + 0.4);
  const float ox = vcx - 0.4f;
  const float oy = ox;
  const float oz = -1.0f - 4.0f;
  float tx = (gxf - ox) / 0.8f;
  float ty = (gyf - oy) / 0.8f;
  float tz = (gzf - oz) / 8.0f;
  int ix = (int)tx, iy = (int)ty, iz = (int)tz;
  bool valid = (tx==tx) && (ty==ty) && (tz==tz) &&
               (ix >= 0) && (ix < NXg) && (iy >= 0) && (iy < NYg) && (iz == 0);
  int b = img / NN;
  sid[g] = valid ? (b*YX + iy*NXg + ix) : -1;
}

// ---------------- conv GEMM: split-K, implicit im2col, global_load_lds staging ----------------
// Grid (4, 66, KSPLIT). Each block: 128(oc) x 128(pos) over K-chunk blockIdx.z.
// Writes bf16 partials part[z][pos][oc].
__global__ __launch_bounds__(256, 4) void k_conv_sk(const unsigned short* __restrict__ W,
    const unsigned short* __restrict__ src, unsigned short* __restrict__ part){
  __shared__ __align__(16) short As[128*32];
  __shared__ __align__(16) short Bs[128*32];
  int t = threadIdx.x;
  int lane = t & 63, wv = t >> 6;
  int wm = wv >> 1, wn = wv & 1;
  int q = lane >> 4, ml = lane & 15;
  int m0 = blockIdx.x * 128;
  int n0 = blockIdx.y * 128;
  int k0 = blockIdx.z * KCHUNK;

  int lrow = lane >> 2;          // 0..15
  int lcol = (lane & 3) * 8;     // shorts
  const unsigned short* agp[2];
  const unsigned short* bgp[2];
  #pragma unroll
  for (int i=0;i<2;i++){
    int seg = wv*2 + i;
    agp[i] = W + (size_t)(m0 + seg*16 + lrow)*KK + lcol;
    int pos = n0 + seg*16 + lrow;
    int img = pos / NPIX; int p = pos - img*NPIX;
    int y = p / FWw; int x = p - y*FWw;
    bgp[i] = src + (size_t)img*PADPIX*512 + ((y+1)*PROW + (x+1))*512 + lcol;
  }

  f32x4 acc[4][4];
  #pragma unroll
  for (int i=0;i<4;i++)
    #pragma unroll
    for (int j=0;j<4;j++) acc[i][j] = (f32x4)0.0f;

  for (int kb = k0; kb < k0 + KCHUNK; kb += 32){
    int r = kb >> 9;
    int ic0 = kb & 511;
    int r3 = r / 3;
    int koff = (r3*PROW + (r - r3*3))*512 + ic0 - (PROW+1)*512;  // (dy*46+dx)*512 + ic0
    #pragma unroll
    for (int i=0;i<2;i++){
      int seg = wv*2 + i;
      GLD16(agp[i] + kb,   (char*)As + seg*1024);
      GLD16(bgp[i] + koff, (char*)Bs + seg*1024);
    }
    __syncthreads();
    short8 fa[4], fb[4];
    #pragma unroll
    for (int mi=0;mi<4;mi++) fa[mi] = *(const short8*)(As + (wm*64 + mi*16 + ml)*32 + q*8);
    #pragma unroll
    for (int ni=0;ni<4;ni++) fb[ni] = *(const short8*)(Bs + (wn*64 + ni*16 + ml)*32 + q*8);
    #pragma unroll
    for (int mi=0;mi<4;mi++)
      #pragma unroll
      for (int ni=0;ni<4;ni++)
        acc[mi][ni] = mfma16(fb[ni], fa[mi], acc[mi][ni]);   // rows=pos, cols=oc
    __syncthreads();
  }

  unsigned short* op = part + (size_t)blockIdx.z*NPOS*CMID;
  #pragma unroll
  for (int mi=0;mi<4;mi++){
    int oc = m0 + wm*64 + mi*16 + ml;
    #pragma unroll
    for (int ni=0;ni<4;ni++){
      f32x4 v = acc[mi][ni];
      #pragma unroll
      for (int rr=0;rr<4;rr++){
        int pos = n0 + wn*64 + ni*16 + q*4 + rr;
        op[(size_t)pos*CMID + oc] = f2bf(v[rr]);
      }
    }
  }
}

// ---------------- split-K reduce + BN + ReLU + bf16 (2 elems/thread) ----------------
// OUT_PADDED=1: write padded NHWC (for conv2 input); else [pos][512].
template<int OUT_PADDED>
__global__ void k_reduce(const unsigned short* __restrict__ part,
                         const float* __restrict__ scale, const float* __restrict__ bias,
                         unsigned short* __restrict__ out){
  int i2 = blockIdx.x*blockDim.x + threadIdx.x;   // NPOS*CMID/2 exactly
  int e0 = i2*2;
  const size_t S = (size_t)NPOS*CMID;
  unsigned p0 = *(const unsigned*)(part + e0);
  unsigned p1 = *(const unsigned*)(part + e0 + S);
  unsigned p2 = *(const unsigned*)(part + e0 + 2*S);
  unsigned p3 = *(const unsigned*)(part + e0 + 3*S);
  float s0 = bf2f((unsigned short)p0) + bf2f((unsigned short)p1)
           + bf2f((unsigned short)p2) + bf2f((unsigned short)p3);
  float s1 = bf2f((unsigned short)(p0>>16)) + bf2f((unsigned short)(p1>>16))
           + bf2f((unsigned short)(p2>>16)) + bf2f((unsigned short)(p3>>16));
  int pos = e0 >> 9, oc = e0 & 511;
  float v0 = fmaxf(s0*scale[oc]   + bias[oc],   0.0f);
  float v1 = fmaxf(s1*scale[oc+1] + bias[oc+1], 0.0f);
  unsigned packed = (unsigned)f2bf(v0) | ((unsigned)f2bf(v1) << 16);
  if (OUT_PADDED){
    int img = pos / NPIX; int p = pos - img*NPIX;
    int y = p / FWw; int x = p - y*FWw;
    *(unsigned*)(out + (size_t)img*PADPIX*512 + ((y+1)*PROW + (x+1))*512 + oc) = packed;
  } else {
    *(unsigned*)(out + e0) = packed;
  }
}

// ---------------- 1x1 conv-out GEMM: M=192(BM=64), N=8448, K=512 ----------------
__global__ __launch_bounds__(256) void k_gemm64(const unsigned short* __restrict__ A,
    const unsigned short* __restrict__ Bt, const float* __restrict__ bout,
    float* __restrict__ hf){
  const int K = 512;
  __shared__ __align__(16) short As[64][32];
  __shared__ __align__(16) short Bs[128][32];
  int t = threadIdx.x;
  int m0 = blockIdx.x*64; int n0 = blockIdx.y*128;
  int lane = t & 63; int wv = t >> 6; int q = lane >> 4, ml = lane & 15;
  f32x4 acc[8];
  #pragma unroll
  for (int i=0;i<8;i++) acc[i] = (f32x4)0.0f;
  int ar = t >> 2, ac = (t & 3) * 8;
  int br = t >> 1, bc = (t & 1) * 16;
  const unsigned short* pa = A  + (size_t)(m0 + ar)*K + ac;
  const unsigned short* pb = Bt + (size_t)(n0 + br)*K + bc;
  for (int kb = 0; kb < K; kb += 32){
    uint4 av = *(const uint4*)(pa + kb);
    uint4 b0 = *(const uint4*)(pb + kb);
    uint4 b1 = *(const uint4*)(pb + kb + 8);
    __syncthreads();
    *(uint4*)&As[ar][ac] = av;
    *(uint4*)&Bs[br][bc] = b0; *(uint4*)&Bs[br][bc+8] = b1;
    __syncthreads();
    short8 fa = *(const short8*)&As[wv*16 + ml][q*8];
    #pragma unroll
    for (int ni=0;ni<8;ni++){
      short8 fb = *(const short8*)&Bs[ni*16 + ml][q*8];
      acc[ni] = mfma16(fb, fa, acc[ni]);     // rows = pos, cols = oc
    }
  }
  int oc = m0 + wv*16 + ml;
  float bb = bout[oc];
  #pragma unroll
  for (int ni=0;ni<8;ni++)
    #pragma unroll
    for (int r=0;r<4;r++){
      int pos = n0 + ni*16 + q*4 + r;
      hf[(size_t)pos*192 + oc] = acc[ni][r] + bb;
    }
}

// ---------------- depth softmax ----------------
__global__ void k_softmax(const float* __restrict__ hf, float* __restrict__ depth){
  int pos = blockIdx.x*4 + (threadIdx.x >> 6);
  int lane = threadIdx.x & 63;
  const float* row = hf + (size_t)pos*192;
  float v0 = row[lane];
  float v1 = (lane < DD-64) ? row[64 + lane] : -1e30f;
  float mx = fmaxf(v0, v1);
  #pragma unroll
  for (int m=1; m<64; m<<=1) mx = fmaxf(mx, __shfl_xor(mx, m, 64));
  float e0 = expf(v0 - mx);
  float e1 = (lane < DD-64) ? expf(v1 - mx) : 0.0f;
  float s = e0 + e1;
  #pragma unroll
  for (int m=1; m<64; m<<=1) s += __shfl_xor(s, m, 64);
  float inv = 1.0f / s;
  depth[(size_t)pos*DD + lane] = e0 * inv;
  if (lane < DD-64) depth[(size_t)pos*DD + 64 + lane] = e1 * inv;
}

// ---------------- scatter: head-compaction then dense atomic loop ----------------
__global__ void k_scatter(const float* __restrict__ depth, const float* __restrict__ hf,
                          const int* __restrict__ sidb, float* __restrict__ bev){
  int pos = blockIdx.x;
  int img = pos / NPIX; int p = pos - img*NPIX;
  __shared__ float sdep[DD];
  __shared__ int   ssid[DD];
  __shared__ float sctx[COUT];
  __shared__ float cwt[DD];
  __shared__ int   cvox[DD];
  __shared__ int   scnt;
  int t = threadIdx.x;    // 128
  if (t == 0) scnt = 0;
  if (t < DD){
    sdep[t] = depth[(size_t)pos*DD + t];
    ssid[t] = sidb[(size_t)(img*DD + t)*NPIX + p];
  }
  if (t < COUT) sctx[t] = hf[(size_t)pos*192 + DD + t];
  __syncthreads();
  if (t < DD){
    int s = ssid[t];
    bool head = (s >= 0) && (t == 0 || ssid[t-1] != s);
    if (head){
      float w = 0.0f;
      for (int dd = t; dd < DD && ssid[dd] == s; ++dd) w += sdep[dd];
      int i = atomicAdd(&scnt, 1);
      cvox[i] = s; cwt[i] = w;
    }
  }
  __syncthreads();
  int H = scnt;
  for (int j = t; j < H*COUT; j += 128){
    int h = j / COUT, c = j - h*COUT;
    atomicAdd(&bev[(size_t)cvox[h]*COUT + c], cwt[h]*sctx[c]);
  }
}

// ---------------- final transpose, LDS-tiled: [b][yx][c] -> [b][c][yx] ----------------
__global__ __launch_bounds__(256) void k_transpose(const float* __restrict__ bev, float* __restrict__ out){
  __shared__ float tile[64*COUT];
  int blk = blockIdx.x;               // 512 = NB * (YX/64)
  int b = blk >> 8; int yx0 = (blk & 255) * 64;
  int t = threadIdx.x;
  const float* src = bev + ((size_t)b*YX + yx0)*COUT;
  for (int j = t; j < 64*COUT; j += 256) tile[j] = src[j];
  __syncthreads();
  float* dst = out + (size_t)b*COUT*YX + yx0;
  for (int j = t; j < COUT*64; j += 256){
    int c = j >> 6, row = j & 63;
    dst[(size_t)c*YX + row] = tile[row*COUT + c];
  }
}

// ---------------- host ----------------
extern "C" void kernel_launch(void* const* d_in, const int* in_sizes, int n_in,
                              void* d_out, int out_size, void* d_ws, size_t ws_size,
                              hipStream_t stream) {
  const float* feat = (const float*)d_in[0];
  const float* w1   = (const float*)d_in[1];
  const float* g1   = (const float*)d_in[2];
  const float* b1   = (const float*)d_in[3];
  const float* m1   = (const float*)d_in[4];
  const float* v1   = (const float*)d_in[5];
  const float* w2   = (const float*)d_in[6];
  const float* g2   = (const float*)d_in[7];
  const float* b2   = (const float*)d_in[8];
  const float* m2   = (const float*)d_in[9];
  const float* v2   = (const float*)d_in[10];
  const float* wout = (const float*)d_in[11];
  const float* bout = (const float*)d_in[12];
  const float* s2e  = (const float*)d_in[13];
  const float* s2v  = (const float*)d_in[14];
  const float* intr = (const float*)d_in[15];
  const float* ida  = (const float*)d_in[16];
  const float* refh = (const float*)d_in[17];
  const float* bda  = (const float*)d_in[18];

  uint8_t* base = (uint8_t*)d_ws;
  size_t off = 0;
  auto alloc = [&](size_t bytes)->void*{
    void* r = base + off;
    off = (off + bytes + 255) & ~(size_t)255;
    return r;
  };
  unsigned short* wb1 = (unsigned short*)alloc((size_t)CMID*KK*2);
  unsigned short* wb2 = (unsigned short*)alloc((size_t)CMID*KK*2);
  unsigned short* wb3 = (unsigned short*)alloc((size_t)192*CMID*2);
  float* scale1 = (float*)alloc(CMID*4);
  float* bias1  = (float*)alloc(CMID*4);
  float* scale2 = (float*)alloc(CMID*4);
  float* bias2  = (float*)alloc(CMID*4);
  double* mats  = (double*)alloc((size_t)NIMG*MAT_STRIDE*8);

  size_t padded_bytes = (size_t)NIMG*PADPIX*512*2;          // 10.2 MB
  uint8_t* regionE = (uint8_t*)alloc(padded_bytes);
  uint8_t* regionF = (uint8_t*)alloc(padded_bytes);
  float* depth = (float*)alloc((size_t)NPOS*DD*4);
  int*   sid   = (int*)  alloc((size_t)NIMG*DD*NPIX*4);
  float* bev   = (float*)alloc((size_t)NB*YX*COUT*4);
  unsigned short* part = (unsigned short*)alloc((size_t)KSPLIT*NPOS*CMID*2); // 34.6 MB

  unsigned short* featpad = (unsigned short*)regionE;
  unsigned short* h2      = (unsigned short*)regionE;
  unsigned short* h1pad   = (unsigned short*)regionF;
  float*          hf      = (float*)regionF;

  // prep (fused)
  int prep_n = 2*N1 + 192*CMID + 1024;
  k_prep_misc<<<(prep_n + 255)/256, 256, 0, stream>>>(w1, w2, wout, g1, b1, m1, v1,
      g2, b2, m2, v2, wb1, wb2, wb3, scale1, bias1, scale2, bias2);
  k_prep_mats<<<1, 64, 0, stream>>>(s2e, s2v, intr, ida, refh, bda, mats);
  k_geom<<<3696, 256, 0, stream>>>(mats, sid);

  k_zeropad<<<3072, 256, 0, stream>>>(featpad, h1pad);
  k_featpad<<<192, 256, 0, stream>>>(feat, featpad);

  // conv1: featpad -> partials -> h1pad (padded NHWC bf16)
  k_conv_sk<<<dim3(4, 66, KSPLIT), 256, 0, stream>>>(wb1, featpad, part);
  k_reduce<1><<<NPOS*CMID/512, 256, 0, stream>>>(part, scale1, bias1, h1pad);
  // conv2: h1pad -> partials -> h2 ([pos][512] bf16)
  k_conv_sk<<<dim3(4, 66, KSPLIT), 256, 0, stream>>>(wb2, h1pad, part);
  k_reduce<0><<<NPOS*CMID/512, 256, 0, stream>>>(part, scale2, bias2, h2);
  // conv3 (1x1): h2 -> hf ([pos][192] fp32, +b_out)
  k_gemm64<<<dim3(3, 66), 256, 0, stream>>>(wb3, h2, bout, hf);

  k_softmax<<<2112, 256, 0, stream>>>(hf, depth);

  hipMemsetAsync(bev, 0, (size_t)NB*YX*COUT*4, stream);
  k_scatter<<<NPOS, 128, 0, stream>>>(depth, hf, sid, bev);

  k_transpose<<<512, 256, 0, stream>>>(bev, (float*)d_out);
}

// Round 6
// 371.122 us; speedup vs baseline: 1.5724x; 1.0637x over previous
//
#include <hip/hip_runtime.h>
#include <stdint.h>

#define NB   2
#define NN   6
#define NIMG 12
#define CIN  512
#define CMID 512
#define DD   112
#define COUT 80
#define FHh  16
#define FWw  44
#define NPIX 704
#define NPOS 8448
#define KK   4608       // 512*9, k = r*512 + ic
#define NXg  128
#define NYg  128
#define YX   16384
#define MAT_STRIDE 56
#define PADPIX 828      // 18*46 padded image
#define PROW 46
#define KSPLIT 4
#define KCHUNK (KK/KSPLIT)   // 1152
#define NSTEP (KCHUNK/32)    // 36

typedef short short8 __attribute__((ext_vector_type(8)));
typedef float f32x4  __attribute__((ext_vector_type(4)));

#define GLD16(g, l) __builtin_amdgcn_global_load_lds((const __attribute__((address_space(1))) void*)(g), (__attribute__((address_space(3))) void*)(l), 16, 0, 0)

__device__ __forceinline__ unsigned short f2bf(float f){
  unsigned u = __float_as_uint(f);
  u += 0x7fffu + ((u >> 16) & 1u);    // RNE
  return (unsigned short)(u >> 16);
}
__device__ __forceinline__ float bf2f(unsigned short u){
  return __uint_as_float(((unsigned)u) << 16);
}

__device__ __forceinline__ f32x4 mfma16(short8 a, short8 b, f32x4 c){
  return __builtin_amdgcn_mfma_f32_16x16x32_bf16(a, b, c, 0, 0, 0);
}

// ---------------- fused prep: wb1, wb2, wb3, BN scale/bias ----------------
#define N1 (CMID*KK)   // 2359296
__global__ void k_prep_misc(const float* __restrict__ w1, const float* __restrict__ w2,
                            const float* __restrict__ wout,
                            const float* __restrict__ g1, const float* __restrict__ b1,
                            const float* __restrict__ m1, const float* __restrict__ v1,
                            const float* __restrict__ g2, const float* __restrict__ b2,
                            const float* __restrict__ m2, const float* __restrict__ v2,
                            unsigned short* __restrict__ wb1, unsigned short* __restrict__ wb2,
                            unsigned short* __restrict__ wb3,
                            float* __restrict__ scale1, float* __restrict__ bias1,
                            float* __restrict__ scale2, float* __restrict__ bias2){
  int i = blockIdx.x*blockDim.x + threadIdx.x;
  if (i < 2*N1){
    const float* w = (i < N1) ? w1 : w2;
    unsigned short* wb = (i < N1) ? wb1 : wb2;
    int j = (i < N1) ? i : i - N1;
    int oc = j / KK; int jj = j - oc*KK;
    int r = jj >> 9; int ic = jj & 511;
    wb[j] = f2bf(w[(size_t)(oc*512 + ic)*9 + r]);
  } else if (i < 2*N1 + 192*CMID){
    int j = i - 2*N1;
    wb3[j] = f2bf(wout[j]);
  } else if (i < 2*N1 + 192*CMID + 512){
    int t = i - (2*N1 + 192*CMID);
    float s = g1[t] / sqrtf(v1[t] + 1e-5f);
    scale1[t] = s; bias1[t] = b1[t] - m1[t]*s;
  } else if (i < 2*N1 + 192*CMID + 1024){
    int t = i - (2*N1 + 192*CMID + 512);
    float s = g2[t] / sqrtf(v2[t] + 1e-5f);
    scale2[t] = s; bias2[t] = b2[t] - m2[t]*s;
  }
}

// ---------------- border-zero for padded buffers + bev zero ----------------
__global__ void k_zeropad(unsigned short* __restrict__ a, unsigned short* __restrict__ b,
                          float4* __restrict__ bev){
  int i = blockIdx.x*blockDim.x + threadIdx.x;   // 786432 exactly
  if (i < NB*YX*COUT/4) bev[i] = make_float4(0.f,0.f,0.f,0.f);
  int img = i >> 16; int j = i & 65535;
  int seg = j >> 9, ch = j & 511;
  int pp;
  if (seg < 46)       pp = seg;                       // row y=0
  else if (seg < 92)  pp = 17*PROW + (seg - 46);      // row y=17
  else { int s2 = seg - 92; int y = s2 >> 1; pp = y*PROW + ((s2 & 1) ? 45 : 0); }
  size_t off = (size_t)img*PADPIX*512 + (size_t)pp*512 + ch;
  a[off] = 0; b[off] = 0;
}

// feat fp32 NCHW -> padded channels-last bf16 [img][PADPIX][512]; LDS-tiled transpose
__global__ __launch_bounds__(256) void k_featpad(const float* __restrict__ feat,
                                                 unsigned short* __restrict__ dst){
  __shared__ float tile[32][65];
  int blk = blockIdx.x;                 // 12*16*11 = 2112
  int img = blk / 176; int r = blk - img*176;
  int cb = r / 11; int pb = r - cb*11;
  int c0 = cb*32, p0 = pb*64;
  int t = threadIdx.x;
  const float* s = feat + (size_t)img*CIN*NPIX + (size_t)c0*NPIX + p0;
  for (int ch = t>>6; ch < 32; ch += 4)
    tile[ch][t & 63] = s[(size_t)ch*NPIX + (t & 63)];
  __syncthreads();
  int ch = (t & 15)*2;
  for (int pix = t>>4; pix < 64; pix += 16){
    int p = p0 + pix;
    int y = p / FWw, x = p - y*FWw;
    unsigned v = (unsigned)f2bf(tile[ch][pix]) | ((unsigned)f2bf(tile[ch+1][pix]) << 16);
    *(unsigned*)(dst + (size_t)img*PADPIX*512 + ((y+1)*PROW + (x+1))*512 + c0 + ch) = v;
  }
}

__device__ void inv4(const double* A, double* out){
  double M[4][8];
  for (int i=0;i<4;i++){ for(int j=0;j<4;j++){ M[i][j]=A[i*4+j]; M[i][4+j]=(i==j)?1.0:0.0; } }
  for (int c=0;c<4;c++){
    int piv=c; double best=fabs(M[c][c]);
    for (int r=c+1;r<4;r++){ double a=fabs(M[r][c]); if(a>best){best=a;piv=r;} }
    if (piv!=c){ for(int j=0;j<8;j++){ double tt=M[c][j]; M[c][j]=M[piv][j]; M[piv][j]=tt; } }
    double inv = 1.0 / M[c][c];
    for (int j=0;j<8;j++) M[c][j]*=inv;
    for (int r=0;r<4;r++){ if(r==c) continue; double f=M[r][c];
      for (int j=0;j<8;j++) M[r][j]-=f*M[c][j]; }
  }
  for (int i=0;i<4;i++) for(int j=0;j<4;j++) out[i*4+j]=M[i][4+j];
}
__device__ void mm4(const double* A, const double* Bm, double* C){
  for (int i=0;i<4;i++) for(int j=0;j<4;j++){
    double s=0.0; for(int k=0;k<4;k++) s+=A[i*4+k]*Bm[k*4+j]; C[i*4+j]=s; }
}

__global__ void k_prep_mats(const float* __restrict__ s2e, const float* __restrict__ s2v,
                            const float* __restrict__ intr, const float* __restrict__ ida,
                            const float* __restrict__ refh, const float* __restrict__ bda,
                            double* __restrict__ mats){
  int t = threadIdx.x;
  if (t >= NIMG) return;
  int b = t / NN;
  double Mida[16], Ms2v[16], Mintr[16], Ms2e[16], Mbda[16];
  for (int i=0;i<16;i++){
    Mida[i] =(double)ida [t*16+i];
    Ms2v[i] =(double)s2v [t*16+i];
    Mintr[i]=(double)intr[t*16+i];
    Ms2e[i] =(double)s2e [t*16+i];
    Mbda[i] =(double)bda [b*16+i];
  }
  double* o = mats + (size_t)t*MAT_STRIDE;
  double tmp[16], tmp2[16];
  inv4(Mida, o);
  inv4(Mintr, tmp);  mm4(Ms2v, tmp, o+16);
  inv4(Ms2v, tmp);   mm4(Ms2e, tmp, tmp2);
  mm4(Mbda, tmp2, o+32);
  o[48] = (double)refh[t];
}

// ---------------- geometry ----------------
__global__ void k_geom(const double* __restrict__ mats, int* __restrict__ sid){
  int g = blockIdx.x*blockDim.x + threadIdx.x;       // 946176 exactly
  int img = g / (DD*NPIX); int rem = g - img*(DD*NPIX);
  int d = rem / NPIX; int p = rem - d*NPIX;
  int h = p / FWw; int w = p - h*FWw;
  const double* M = mats + (size_t)img*MAT_STRIDE;
  float xf = (float)w * (703.0f/43.0f);
  float yf = (float)h * 17.0f;
  float df = 2.0f + (float)d * (56.0f/111.0f);
  double x = (double)xf, y = (double)yf, dep = (double)df;
  double p0 = M[0]*x + M[1]*y + M[2]*dep + M[3];
  double p1 = M[4]*x + M[5]*y + M[6]*dep + M[7];
  double p2 = M[8]*x + M[9]*y + M[10]*dep + M[11];
  double p3 = M[12]*x + M[13]*y + M[14]*dep + M[15];
  double height = M[48] - p2;
  double c0 = p0*10.0, c1 = p1*10.0, c2 = 10.0, c3 = p3;
  const double* C = M + 16;
  double q0 = C[0]*c0 + C[1]*c1 + C[2]*c2 + C[3]*c3;
  double q1 = C[4]*c0 + C[5]*c1 + C[6]*c2 + C[7]*c3;
  double q2 = C[8]*c0 + C[9]*c1 + C[10]*c2 + C[11]*c3;
  double ratio = height / q1;
  double r0 = q0*ratio, r1 = q1*ratio, r2 = q2*ratio, r3 = 1.0;
  const double* F = M + 32;
  double gx = F[0]*r0 + F[1]*r1 + F[2]*r2 + F[3]*r3;
  double gy = F[4]*r0 + F[5]*r1 + F[6]*r2 + F[7]*r3;
  double gz = F[8]*r0 + F[9]*r1 + F[10]*r2 + F[11]*r3;
  float gxf = (float)gx, gyf = (float)gy, gzf = (float)gz;
  const float vcx = (float)(-51.2 + 0.4);
  const float ox = vcx - 0.4f;
  const float oy = ox;
  const float oz = -1.0f - 4.0f;
  float tx = (gxf - ox) / 0.8f;
  float ty = (gyf - oy) / 0.8f;
  float tz = (gzf - oz) / 8.0f;
  int ix = (int)tx, iy = (int)ty, iz = (int)tz;
  bool valid = (tx==tx) && (ty==ty) && (tz==tz) &&
               (ix >= 0) && (ix < NXg) && (iy >= 0) && (iy < NYg) && (iz == 0);
  int b = img / NN;
  sid[g] = valid ? (b*YX + iy*NXg + ix) : -1;
}

// ---------------- conv GEMM: split-K, implicit im2col, XCD-swizzled, dbuf + split vmcnt ----
// 1D grid 1056. Decode puts the 4 m-blocks of each (n,z) group on one XCD (id%8 residue).
// Writes bf16 partials part[z][pos][oc].
__global__ __launch_bounds__(256, 4) void k_conv_sk(const unsigned short* __restrict__ W,
    const unsigned short* __restrict__ src, unsigned short* __restrict__ part){
  __shared__ __align__(16) short As[2][128*32];   // 2 x 8 KB
  __shared__ __align__(16) short Bs[2][128*32];   // 2 x 8 KB
  int t = threadIdx.x;
  int lane = t & 63, wv = t >> 6;
  int wm = wv >> 1, wn = wv & 1;
  int q = lane >> 4, ml = lane & 15;

  // XCD swizzle: id%8 = XCD residue; 4 consecutive slots per residue = one (n,z) group
  int id = blockIdx.x;
  int res = id & 7, slot = id >> 3;       // slot 0..131
  int g = res + 8*(slot >> 2);            // 0..263 group = (n,z)
  int mblk = slot & 3;
  int z = g / 66, n = g - z*66;
  int m0 = mblk*128, n0 = n*128, k0 = z*KCHUNK;

  int lrow = lane >> 2;          // 0..15
  int lcol = (lane & 3) * 8;     // shorts
  const unsigned short* agp[2];
  const unsigned short* bgp[2];
  #pragma unroll
  for (int i=0;i<2;i++){
    int seg = wv*2 + i;
    agp[i] = W + (size_t)(m0 + seg*16 + lrow)*KK + lcol;
    int pos = n0 + seg*16 + lrow;
    int img = pos / NPIX; int p = pos - img*NPIX;
    int y = p / FWw; int x = p - y*FWw;
    bgp[i] = src + (size_t)img*PADPIX*512 + ((y+1)*PROW + (x+1))*512 + lcol;
  }

  f32x4 acc[4][4];
  #pragma unroll
  for (int i=0;i<4;i++)
    #pragma unroll
    for (int j=0;j<4;j++) acc[i][j] = (f32x4)0.0f;

  auto stage = [&](int step){
    int kb = k0 + step*32;
    int d = step & 1;
    int r = kb >> 9;
    int ic0 = kb & 511;
    int r3 = r / 3;
    int koff = (r3*PROW + (r - r3*3))*512 + ic0 - (PROW+1)*512;
    #pragma unroll
    for (int i=0;i<2;i++){
      int seg = wv*2 + i;
      GLD16(agp[i] + kb,   (char*)As[d] + seg*1024);
      GLD16(bgp[i] + koff, (char*)Bs[d] + seg*1024);
    }
  };

  stage(0);
  for (int k = 0; k < NSTEP; ++k){
    if (k + 1 < NSTEP){
      stage(k + 1);
      asm volatile("s_waitcnt vmcnt(4)" ::: "memory");   // step k's 4 loads done; k+1's in flight
    } else {
      asm volatile("s_waitcnt vmcnt(0)" ::: "memory");
    }
    asm volatile("s_barrier" ::: "memory");
    const short* Ab = As[k & 1];
    const short* Bb = Bs[k & 1];
    short8 fa[4], fb[4];
    #pragma unroll
    for (int mi=0;mi<4;mi++) fa[mi] = *(const short8*)(Ab + (wm*64 + mi*16 + ml)*32 + q*8);
    #pragma unroll
    for (int ni=0;ni<4;ni++) fb[ni] = *(const short8*)(Bb + (wn*64 + ni*16 + ml)*32 + q*8);
    #pragma unroll
    for (int mi=0;mi<4;mi++)
      #pragma unroll
      for (int ni=0;ni<4;ni++)
        acc[mi][ni] = mfma16(fb[ni], fa[mi], acc[mi][ni]);   // rows=pos, cols=oc
    asm volatile("s_barrier" ::: "memory");    // protect buf k&1 before step k+2 overwrites it
  }

  unsigned short* op = part + (size_t)z*NPOS*CMID;
  #pragma unroll
  for (int mi=0;mi<4;mi++){
    int oc = m0 + wm*64 + mi*16 + ml;
    #pragma unroll
    for (int ni=0;ni<4;ni++){
      f32x4 v = acc[mi][ni];
      #pragma unroll
      for (int rr=0;rr<4;rr++){
        int pos = n0 + wn*64 + ni*16 + q*4 + rr;
        op[(size_t)pos*CMID + oc] = f2bf(v[rr]);
      }
    }
  }
}

// ---------------- split-K reduce + BN + ReLU + bf16 (2 elems/thread) ----------------
template<int OUT_PADDED>
__global__ void k_reduce(const unsigned short* __restrict__ part,
                         const float* __restrict__ scale, const float* __restrict__ bias,
                         unsigned short* __restrict__ out){
  int i2 = blockIdx.x*blockDim.x + threadIdx.x;   // NPOS*CMID/2 exactly
  int e0 = i2*2;
  const size_t S = (size_t)NPOS*CMID;
  unsigned p0 = *(const unsigned*)(part + e0);
  unsigned p1 = *(const unsigned*)(part + e0 + S);
  unsigned p2 = *(const unsigned*)(part + e0 + 2*S);
  unsigned p3 = *(const unsigned*)(part + e0 + 3*S);
  float s0 = bf2f((unsigned short)p0) + bf2f((unsigned short)p1)
           + bf2f((unsigned short)p2) + bf2f((unsigned short)p3);
  float s1 = bf2f((unsigned short)(p0>>16)) + bf2f((unsigned short)(p1>>16))
           + bf2f((unsigned short)(p2>>16)) + bf2f((unsigned short)(p3>>16));
  int pos = e0 >> 9, oc = e0 & 511;
  float v0 = fmaxf(s0*scale[oc]   + bias[oc],   0.0f);
  float v1 = fmaxf(s1*scale[oc+1] + bias[oc+1], 0.0f);
  unsigned packed = (unsigned)f2bf(v0) | ((unsigned)f2bf(v1) << 16);
  if (OUT_PADDED){
    int img = pos / NPIX; int p = pos - img*NPIX;
    int y = p / FWw; int x = p - y*FWw;
    *(unsigned*)(out + (size_t)img*PADPIX*512 + ((y+1)*PROW + (x+1))*512 + oc) = packed;
  } else {
    *(unsigned*)(out + e0) = packed;
  }
}

// ---------------- 1x1 conv-out GEMM: M=192(BM=64), N=8448, K=512 ----------------
__global__ __launch_bounds__(256) void k_gemm64(const unsigned short* __restrict__ A,
    const unsigned short* __restrict__ Bt, const float* __restrict__ bout,
    float* __restrict__ hf){
  const int K = 512;
  __shared__ __align__(16) short As[64][32];
  __shared__ __align__(16) short Bs[128][32];
  int t = threadIdx.x;
  int m0 = blockIdx.x*64; int n0 = blockIdx.y*128;
  int lane = t & 63; int wv = t >> 6; int q = lane >> 4, ml = lane & 15;
  f32x4 acc[8];
  #pragma unroll
  for (int i=0;i<8;i++) acc[i] = (f32x4)0.0f;
  int ar = t >> 2, ac = (t & 3) * 8;
  int br = t >> 1, bc = (t & 1) * 16;
  const unsigned short* pa = A  + (size_t)(m0 + ar)*K + ac;
  const unsigned short* pb = Bt + (size_t)(n0 + br)*K + bc;
  for (int kb = 0; kb < K; kb += 32){
    uint4 av = *(const uint4*)(pa + kb);
    uint4 b0 = *(const uint4*)(pb + kb);
    uint4 b1 = *(const uint4*)(pb + kb + 8);
    __syncthreads();
    *(uint4*)&As[ar][ac] = av;
    *(uint4*)&Bs[br][bc] = b0; *(uint4*)&Bs[br][bc+8] = b1;
    __syncthreads();
    short8 fa = *(const short8*)&As[wv*16 + ml][q*8];
    #pragma unroll
    for (int ni=0;ni<8;ni++){
      short8 fb = *(const short8*)&Bs[ni*16 + ml][q*8];
      acc[ni] = mfma16(fb, fa, acc[ni]);     // rows = pos, cols = oc
    }
  }
  int oc = m0 + wv*16 + ml;
  float bb = bout[oc];
  #pragma unroll
  for (int ni=0;ni<8;ni++)
    #pragma unroll
    for (int r=0;r<4;r++){
      int pos = n0 + ni*16 + q*4 + r;
      hf[(size_t)pos*192 + oc] = acc[ni][r] + bb;
    }
}

// ---------------- depth softmax ----------------
__global__ void k_softmax(const float* __restrict__ hf, float* __restrict__ depth){
  int pos = blockIdx.x*4 + (threadIdx.x >> 6);
  int lane = threadIdx.x & 63;
  const float* row = hf + (size_t)pos*192;
  float v0 = row[lane];
  float v1 = (lane < DD-64) ? row[64 + lane] : -1e30f;
  float mx = fmaxf(v0, v1);
  #pragma unroll
  for (int m=1; m<64; m<<=1) mx = fmaxf(mx, __shfl_xor(mx, m, 64));
  float e0 = expf(v0 - mx);
  float e1 = (lane < DD-64) ? expf(v1 - mx) : 0.0f;
  float s = e0 + e1;
  #pragma unroll
  for (int m=1; m<64; m<<=1) s += __shfl_xor(s, m, 64);
  float inv = 1.0f / s;
  depth[(size_t)pos*DD + lane] = e0 * inv;
  if (lane < DD-64) depth[(size_t)pos*DD + 64 + lane] = e1 * inv;
}

// ---------------- scatter: head-compaction then dense atomic loop ----------------
__global__ void k_scatter(const float* __restrict__ depth, const float* __restrict__ hf,
                          const int* __restrict__ sidb, float* __restrict__ bev){
  int pos = blockIdx.x;
  int img = pos / NPIX; int p = pos - img*NPIX;
  __shared__ float sdep[DD];
  __shared__ int   ssid[DD];
  __shared__ float sctx[COUT];
  __shared__ float cwt[DD];
  __shared__ int   cvox[DD];
  __shared__ int   scnt;
  int t = threadIdx.x;    // 128
  if (t == 0) scnt = 0;
  if (t < DD){
    sdep[t] = depth[(size_t)pos*DD + t];
    ssid[t] = sidb[(size_t)(img*DD + t)*NPIX + p];
  }
  if (t < COUT) sctx[t] = hf[(size_t)pos*192 + DD + t];
  __syncthreads();
  if (t < DD){
    int s = ssid[t];
    bool head = (s >= 0) && (t == 0 || ssid[t-1] != s);
    if (head){
      float w = 0.0f;
      for (int dd = t; dd < DD && ssid[dd] == s; ++dd) w += sdep[dd];
      int i = atomicAdd(&scnt, 1);
      cvox[i] = s; cwt[i] = w;
    }
  }
  __syncthreads();
  int H = scnt;
  for (int j = t; j < H*COUT; j += 128){
    int h = j / COUT, c = j - h*COUT;
    atomicAdd(&bev[(size_t)cvox[h]*COUT + c], cwt[h]*sctx[c]);
  }
}

// ---------------- final transpose, LDS-tiled: [b][yx][c] -> [b][c][yx] ----------------
__global__ __launch_bounds__(256) void k_transpose(const float* __restrict__ bev, float* __restrict__ out){
  __shared__ float tile[64*COUT];
  int blk = blockIdx.x;               // 512 = NB * (YX/64)
  int b = blk >> 8; int yx0 = (blk & 255) * 64;
  int t = threadIdx.x;
  const float* src = bev + ((size_t)b*YX + yx0)*COUT;
  for (int j = t; j < 64*COUT; j += 256) tile[j] = src[j];
  __syncthreads();
  float* dst = out + (size_t)b*COUT*YX + yx0;
  for (int j = t; j < COUT*64; j += 256){
    int c = j >> 6, row = j & 63;
    dst[(size_t)c*YX + row] = tile[row*COUT + c];
  }
}

// ---------------- host ----------------
extern "C" void kernel_launch(void* const* d_in, const int* in_sizes, int n_in,
                              void* d_out, int out_size, void* d_ws, size_t ws_size,
                              hipStream_t stream) {
  const float* feat = (const float*)d_in[0];
  const float* w1   = (const float*)d_in[1];
  const float* g1   = (const float*)d_in[2];
  const float* b1   = (const float*)d_in[3];
  const float* m1   = (const float*)d_in[4];
  const float* v1   = (const float*)d_in[5];
  const float* w2   = (const float*)d_in[6];
  const float* g2   = (const float*)d_in[7];
  const float* b2   = (const float*)d_in[8];
  const float* m2   = (const float*)d_in[9];
  const float* v2   = (const float*)d_in[10];
  const float* wout = (const float*)d_in[11];
  const float* bout = (const float*)d_in[12];
  const float* s2e  = (const float*)d_in[13];
  const float* s2v  = (const float*)d_in[14];
  const float* intr = (const float*)d_in[15];
  const float* ida  = (const float*)d_in[16];
  const float* refh = (const float*)d_in[17];
  const float* bda  = (const float*)d_in[18];

  uint8_t* base = (uint8_t*)d_ws;
  size_t off = 0;
  auto alloc = [&](size_t bytes)->void*{
    void* r = base + off;
    off = (off + bytes + 255) & ~(size_t)255;
    return r;
  };
  unsigned short* wb1 = (unsigned short*)alloc((size_t)CMID*KK*2);
  unsigned short* wb2 = (unsigned short*)alloc((size_t)CMID*KK*2);
  unsigned short* wb3 = (unsigned short*)alloc((size_t)192*CMID*2);
  float* scale1 = (float*)alloc(CMID*4);
  float* bias1  = (float*)alloc(CMID*4);
  float* scale2 = (float*)alloc(CMID*4);
  float* bias2  = (float*)alloc(CMID*4);
  double* mats  = (double*)alloc((size_t)NIMG*MAT_STRIDE*8);

  size_t padded_bytes = (size_t)NIMG*PADPIX*512*2;          // 10.2 MB
  uint8_t* regionE = (uint8_t*)alloc(padded_bytes);
  uint8_t* regionF = (uint8_t*)alloc(padded_bytes);
  float* depth = (float*)alloc((size_t)NPOS*DD*4);
  int*   sid   = (int*)  alloc((size_t)NIMG*DD*NPIX*4);
  float* bev   = (float*)alloc((size_t)NB*YX*COUT*4);
  unsigned short* part = (unsigned short*)alloc((size_t)KSPLIT*NPOS*CMID*2); // 34.6 MB

  unsigned short* featpad = (unsigned short*)regionE;
  unsigned short* h2      = (unsigned short*)regionE;
  unsigned short* h1pad   = (unsigned short*)regionF;
  float*          hf      = (float*)regionF;

  // prep (fused)
  int prep_n = 2*N1 + 192*CMID + 1024;
  k_prep_misc<<<(prep_n + 255)/256, 256, 0, stream>>>(w1, w2, wout, g1, b1, m1, v1,
      g2, b2, m2, v2, wb1, wb2, wb3, scale1, bias1, scale2, bias2);
  k_prep_mats<<<1, 64, 0, stream>>>(s2e, s2v, intr, ida, refh, bda, mats);
  k_geom<<<3696, 256, 0, stream>>>(mats, sid);

  k_zeropad<<<3072, 256, 0, stream>>>(featpad, h1pad, (float4*)bev);
  k_featpad<<<2112, 256, 0, stream>>>(feat, featpad);

  // conv1: featpad -> partials -> h1pad (padded NHWC bf16)
  k_conv_sk<<<1056, 256, 0, stream>>>(wb1, featpad, part);
  k_reduce<1><<<NPOS*CMID/512, 256, 0, stream>>>(part, scale1, bias1, h1pad);
  // conv2: h1pad -> partials -> h2 ([pos][512] bf16)
  k_conv_sk<<<1056, 256, 0, stream>>>(wb2, h1pad, part);
  k_reduce<0><<<NPOS*CMID/512, 256, 0, stream>>>(part, scale2, bias2, h2);
  // conv3 (1x1): h2 -> hf ([pos][192] fp32, +b_out)
  k_gemm64<<<dim3(3, 66), 256, 0, stream>>>(wb3, h2, bout, hf);

  k_softmax<<<2112, 256, 0, stream>>>(hf, depth);

  k_scatter<<<NPOS, 128, 0, stream>>>(depth, hf, sid, bev);

  k_transpose<<<512, 256, 0, stream>>>(bev, (float*)d_out);
}